// Round 5
// baseline (790.562 us; speedup 1.0000x reference)
//
#include <hip/hip_runtime.h>
#include <stdint.h>

#define N_NODES 50000
#define N_EDGES 800000
#define BB 2
#define F0 216
#define ROWS (BB*N_NODES)   // 100000
#define BN_EPS 1e-5f
#define NSB 49              // ceil(N_NODES/1024)
#define KC2 12              // W chunk (double-buffered)
#define TM 32               // gemm1 row tile: 100000 = 3125*32 exactly

// ---------------- CSR build ----------------
// edge_index arrives as int32 [2, E]

__global__ void k_count(const int* __restrict__ ei, int* __restrict__ cnt) {
    int e = blockIdx.x*blockDim.x + threadIdx.x;
    if (e < N_EDGES) {
        int c = ei[N_EDGES + e];
        atomicAdd(&cnt[c], 1);
    }
}

// scanA also produces dinv
__global__ void k_scanA(const int* __restrict__ cnt, int* __restrict__ incl, int* __restrict__ part,
                        float* __restrict__ dinv) {
    __shared__ int s[1024];
    int t = threadIdx.x;
    int i = blockIdx.x*1024 + t;
    int c = (i < N_NODES) ? cnt[i] : 0;
    if (i < N_NODES) dinv[i] = rsqrtf((float)(c + 1));  // +1 self loop
    s[t] = c;
    __syncthreads();
    for (int off=1; off<1024; off<<=1) {
        int a = (t >= off) ? s[t-off] : 0;
        __syncthreads();
        s[t] += a;
        __syncthreads();
    }
    if (i < N_NODES) incl[i] = s[t];
    if (t == 1023) part[blockIdx.x] = s[t];
}

__global__ void k_scanB(int* part) {
    if (threadIdx.x == 0 && blockIdx.x == 0) {
        int run = 0;
        for (int b=0; b<NSB; b++) { int v = part[b]; part[b] = run; run += v; }
    }
}

__global__ void k_scanC(const int* __restrict__ cnt, const int* __restrict__ incl, const int* __restrict__ part,
                        int* __restrict__ offs, int* __restrict__ cursor) {
    int i = blockIdx.x*1024 + threadIdx.x;
    if (i < N_NODES) {
        int inc = part[blockIdx.x] + incl[i];
        int ex = inc - cnt[i];
        offs[i] = ex; cursor[i] = ex;
        if (i == N_NODES-1) offs[N_NODES] = inc;
    }
}

__global__ void k_fill(const int* __restrict__ ei, const float* __restrict__ dinv,
                       int* __restrict__ cursor, int* __restrict__ csr_src, float* __restrict__ csr_w) {
    int e = blockIdx.x*blockDim.x + threadIdx.x;
    if (e < N_EDGES) {
        int r = ei[e];
        int c = ei[N_EDGES + e];
        int slot = atomicAdd(&cursor[c], 1);
        csr_src[slot] = r;
        csr_w[slot]  = dinv[r];
    }
}

// ---------------- Layer 1 GEMM: xw[100k,64] = x[100k,216] @ W1 ----------------
// v4: 32-row LDS tile (5 blocks/CU), coalesced staging, W double-buffered in
// registers (KC2=12): chunk c+1 loads issued BEFORE chunk c's FMAs so the
// vmcnt wait lands after ~192 cycles of compute (T14 issue-early pattern).
__global__ __launch_bounds__(256,4) void k_gemm1(const float* __restrict__ x, const float* __restrict__ W1,
                                                 float* __restrict__ xw) {
    __shared__ float xs[TM*F0];        // 27648 B
    int t = threadIdx.x;
    int row0 = blockIdx.x * TM;        // exact tiling, no tail

    const float4* xg = reinterpret_cast<const float4*>(x + (size_t)row0 * F0);
    float4* xs4 = reinterpret_cast<float4*>(xs);
    #pragma unroll
    for (int i = 0; i < 7; i++) {
        int idx = t + i*256;
        if (idx < (TM*F0)/4) xs4[idx] = xg[idx];   // fully coalesced
    }
    __syncthreads();

    int o2 = t & 31;                   // cols o2, o2+32
    int rw = t >> 5;                   // 0..7 -> rows rw*4 .. rw*4+3
    float acc0[4] = {0.f,0.f,0.f,0.f};
    float acc1[4] = {0.f,0.f,0.f,0.f};
    float wA0[KC2], wB0[KC2], wA1[KC2], wB1[KC2];   // named double buffers (static idx)

    auto loadW = [&](int c, float (&A)[KC2], float (&Bf)[KC2]) {
        const float* wp = W1 + (size_t)c*KC2*64 + o2;
        #pragma unroll
        for (int kk = 0; kk < KC2; kk++) {
            A[kk]  = wp[kk*64];
            Bf[kk] = wp[kk*64 + 32];
        }
    };
    auto comp = [&](int c, const float (&A)[KC2], const float (&Bf)[KC2]) {
        #pragma unroll
        for (int j = 0; j < 4; j++) {
            const float* xr = xs + (rw*4 + j)*F0 + c*KC2;
            #pragma unroll
            for (int kq = 0; kq < KC2/4; kq++) {
                float4 xv = *reinterpret_cast<const float4*>(xr + 4*kq);
                acc0[j] += xv.x*A[4*kq]  + xv.y*A[4*kq+1]  + xv.z*A[4*kq+2]  + xv.w*A[4*kq+3];
                acc1[j] += xv.x*Bf[4*kq] + xv.y*Bf[4*kq+1] + xv.z*Bf[4*kq+2] + xv.w*Bf[4*kq+3];
            }
        }
    };

    const int NCH = F0/KC2;            // 18 (even)
    loadW(0, wA0, wB0);
    for (int c = 0; c < NCH; c += 2) {
        if (c+1 < NCH) loadW(c+1, wA1, wB1);   // prefetch next while computing cur
        comp(c, wA0, wB0);
        if (c+2 < NCH) loadW(c+2, wA0, wB0);
        comp(c+1, wA1, wB1);
    }

    #pragma unroll
    for (int j = 0; j < 4; j++) {
        int grow = row0 + rw*4 + j;
        xw[(size_t)grow*64 + o2]      = acc0[j];
        xw[(size_t)grow*64 + o2 + 32] = acc1[j];
    }
}

// ---------------- Propagate 1 (64 feat) + bias + relu + BN1 stats ----------------
// proven round-3 config: 4-deep unroll (8 gathers in flight), grid 2048
__global__ __launch_bounds__(256) void k_prop1(const float* __restrict__ xw, const int* __restrict__ offs,
                       const int* __restrict__ csr_src, const float* __restrict__ csr_w,
                       const float* __restrict__ dinv, const float* __restrict__ b1,
                       float* __restrict__ h, float* __restrict__ stat) {
    __shared__ float lsum[64], lsq[64];
    int t = threadIdx.x;
    if (t < 64) { lsum[t]=0.f; lsq[t]=0.f; }
    __syncthreads();
    int f = t & 63;
    int wid = blockIdx.x*4 + (t>>6);
    int nwaves = gridDim.x*4;
    float bias = b1[f];
    float ls=0.f, lq=0.f;
    for (int d = wid; d < N_NODES; d += nwaves) {
        int s0 = offs[d], s1 = offs[d+1];
        float a0=0.f, a1=0.f, p0=0.f, p1=0.f, q0=0.f, q1=0.f, r0=0.f, r1=0.f;
        int e = s0;
        for (; e+4 <= s1; e += 4) {
            int i0=csr_src[e], i1=csr_src[e+1], i2=csr_src[e+2], i3=csr_src[e+3];
            float w0=csr_w[e], w1=csr_w[e+1], w2=csr_w[e+2], w3=csr_w[e+3];
            a0 += w0*xw[(size_t)i0*64+f];  a1 += w0*xw[(size_t)(N_NODES+i0)*64+f];
            p0 += w1*xw[(size_t)i1*64+f];  p1 += w1*xw[(size_t)(N_NODES+i1)*64+f];
            q0 += w2*xw[(size_t)i2*64+f];  q1 += w2*xw[(size_t)(N_NODES+i2)*64+f];
            r0 += w3*xw[(size_t)i3*64+f];  r1 += w3*xw[(size_t)(N_NODES+i3)*64+f];
        }
        for (; e < s1; e++) {
            int src = csr_src[e]; float w = csr_w[e];
            a0 += w*xw[(size_t)src*64+f];  a1 += w*xw[(size_t)(N_NODES+src)*64+f];
        }
        a0 += p0 + q0 + r0;
        a1 += p1 + q1 + r1;
        float sd = dinv[d];
        a0 += sd * xw[(size_t)d*64 + f];
        a1 += sd * xw[(size_t)(N_NODES+d)*64 + f];
        float h0 = fmaxf(sd*a0 + bias, 0.f);
        float h1 = fmaxf(sd*a1 + bias, 0.f);
        h[(size_t)d*64 + f] = h0;
        h[(size_t)(N_NODES+d)*64 + f] = h1;
        ls += h0 + h1;
        lq += h0*h0 + h1*h1;
    }
    atomicAdd(&lsum[f], ls);
    atomicAdd(&lsq[f], lq);
    __syncthreads();
    if (t < 64) {
        atomicAdd(&stat[t],     lsum[t]);
        atomicAdd(&stat[64+t],  lsq[t]);
    }
}

// ---------------- BN1 finalize + apply + GEMM2 (64->8) ----------------
__global__ __launch_bounds__(256) void k_bn1_gemm2(const float* __restrict__ h, const float* __restrict__ stat,
                        const float* __restrict__ g, const float* __restrict__ be,
                        const float* __restrict__ W2, float* __restrict__ t2) {
    __shared__ float hs[32][68];
    __shared__ float w2s[64*8];
    __shared__ float scS[64], shS[64];
    int t = threadIdx.x;
    if (t < 64) {
        float inv_n = 1.0f / (float)(BB*N_NODES);
        float mean = stat[t]*inv_n;
        float var  = stat[64+t]*inv_n - mean*mean;
        float is   = rsqrtf(var + BN_EPS);
        float scale = g[t]*is;
        scS[t] = scale;
        shS[t] = be[t] - mean*scale;
    }
    for (int i=t; i<512; i+=256) w2s[i] = W2[i];
    __syncthreads();
    int row0 = blockIdx.x*32;
    for (int idx=t; idx<2048; idx+=256) {
        int r = idx>>6, f = idx&63;
        int grow = row0 + r;
        hs[r][f] = (grow < ROWS) ? h[(size_t)grow*64+f]*scS[f] + shS[f] : 0.f;
    }
    __syncthreads();
    int r = t >> 3, o = t & 7;
    float acc = 0.f;
    #pragma unroll
    for (int f=0; f<64; f++) acc += hs[r][f] * w2s[f*8+o];
    int grow = row0 + r;
    if (grow < ROWS) t2[(size_t)grow*8 + o] = acc;
}

// ---------------- Propagate 2 (8 feat) -> x1 out; relu + BN2 stats ----------------
__global__ __launch_bounds__(256) void k_prop2(const float* __restrict__ t2, const int* __restrict__ offs,
                       const int* __restrict__ csr_src, const float* __restrict__ csr_w,
                       const float* __restrict__ dinv, const float* __restrict__ b2,
                       float* __restrict__ x1_out, float* __restrict__ stat) {
    __shared__ float lsum[8], lsq[8];
    int t = threadIdx.x;
    if (t < 8) { lsum[t]=0.f; lsq[t]=0.f; }
    __syncthreads();
    int lane = t & 63;
    int o = lane & 7, b = (lane>>3)&1, es = lane>>4;   // 4 edge-lanes
    int wid = blockIdx.x*4 + (t>>6);
    int nwaves = gridDim.x*4;
    float bias = b2[o];
    float ls=0.f, lq=0.f;
    for (int d=wid; d<N_NODES; d+=nwaves) {
        int s0=offs[d], s1=offs[d+1];
        float accA=0.f, accB=0.f;
        int e = s0 + es;
        for (; e+4 < s1; e += 8) {
            accA += csr_w[e]   * t2[(size_t)(b*N_NODES+csr_src[e])*8 + o];
            accB += csr_w[e+4] * t2[(size_t)(b*N_NODES+csr_src[e+4])*8 + o];
        }
        if (e < s1) accA += csr_w[e] * t2[(size_t)(b*N_NODES+csr_src[e])*8 + o];
        float acc = accA + accB;
        acc += __shfl_xor(acc, 16, 64);
        acc += __shfl_xor(acc, 32, 64);
        float sd = dinv[d];
        float val = sd*(acc + sd*t2[(size_t)(b*N_NODES+d)*8 + o]) + bias;
        if (es == 0) {
            x1_out[(size_t)(b*N_NODES+d)*8 + o] = val;
            float rv = fmaxf(val, 0.f);
            ls += rv; lq += rv*rv;
        }
    }
    if (es == 0) { atomicAdd(&lsum[o], ls); atomicAdd(&lsq[o], lq); }
    __syncthreads();
    if (t < 8) { atomicAdd(&stat[t], lsum[t]); atomicAdd(&stat[8+t], lsq[t]); }
}

// ---------------- BN2 finalize + apply + GEMM3 (8->3), padded to 4 ----------------
__global__ void k_bn2_gemm3(const float* __restrict__ x1, const float* __restrict__ stat,
                            const float* __restrict__ g, const float* __restrict__ be,
                            const float* __restrict__ W3, float* __restrict__ t3) {
    int rowi = blockIdx.x*blockDim.x + threadIdx.x;
    if (rowi < ROWS) {
        float inv_n = 1.0f / (float)(BB*N_NODES);
        float v[8];
        #pragma unroll
        for (int o=0;o<8;o++) {
            float mean = stat[o]*inv_n;
            float var  = stat[8+o]*inv_n - mean*mean;
            float is   = rsqrtf(var + BN_EPS);
            float scale = g[o]*is;
            float shift = be[o] - mean*scale;
            float r = fmaxf(x1[(size_t)rowi*8+o], 0.f);
            v[o] = r*scale + shift;
        }
        #pragma unroll
        for (int c=0;c<3;c++) {
            float acc=0.f;
            #pragma unroll
            for (int o=0;o<8;o++) acc += v[o]*W3[o*3+c];
            t3[(size_t)rowi*4+c] = acc;
        }
        t3[(size_t)rowi*4+3] = 0.f;
    }
}

// ---------------- Propagate 3 (3 feat) + b3 -> final out ----------------
__global__ __launch_bounds__(256) void k_prop3(const float* __restrict__ t3, const int* __restrict__ offs,
                       const int* __restrict__ csr_src, const float* __restrict__ csr_w,
                       const float* __restrict__ dinv, const float* __restrict__ b3,
                       float* __restrict__ outp) {
    int t = threadIdx.x;
    int lane = t & 63;
    int c = lane & 3, b = (lane>>2)&1, es = lane>>3;   // 8 edge-lanes
    int wid = blockIdx.x*4 + (t>>6);
    int nwaves = gridDim.x*4;
    float bias = (c<3) ? b3[c] : 0.f;
    for (int d=wid; d<N_NODES; d+=nwaves) {
        int s0=offs[d], s1=offs[d+1];
        float accA=0.f, accB=0.f;
        int e = s0 + es;
        for (; e+8 < s1; e += 16) {
            accA += csr_w[e]   * t3[(size_t)(b*N_NODES+csr_src[e])*4 + c];
            accB += csr_w[e+8] * t3[(size_t)(b*N_NODES+csr_src[e+8])*4 + c];
        }
        if (e < s1) accA += csr_w[e] * t3[(size_t)(b*N_NODES+csr_src[e])*4 + c];
        float acc = accA + accB;
        acc += __shfl_xor(acc, 8, 64);
        acc += __shfl_xor(acc, 16, 64);
        acc += __shfl_xor(acc, 32, 64);
        float sd = dinv[d];
        float val = sd*(acc + sd*t3[(size_t)(b*N_NODES+d)*4 + c]) + bias;
        if (es == 0 && c < 3) outp[(size_t)(b*N_NODES+d)*3 + c] = val;
    }
}

// ---------------- launch ----------------
static inline size_t align256(size_t x){ return (x + 255) & ~(size_t)255; }

extern "C" void kernel_launch(void* const* d_in, const int* in_sizes, int n_in,
                              void* d_out, int out_size, void* d_ws, size_t ws_size,
                              hipStream_t stream) {
    const float* x   = (const float*)d_in[0];
    const float* W1  = (const float*)d_in[1];
    const float* b1  = (const float*)d_in[2];
    const float* g1  = (const float*)d_in[3];
    const float* be1 = (const float*)d_in[4];
    const float* W2  = (const float*)d_in[5];
    const float* b2  = (const float*)d_in[6];
    const float* g2  = (const float*)d_in[7];
    const float* be2 = (const float*)d_in[8];
    const float* W3  = (const float*)d_in[9];
    const float* b3  = (const float*)d_in[10];
    const int*   ei  = (const int*)d_in[11];     // int32 [2, E]

    float* outp   = (float*)d_out;                 // [B,N,3]
    float* x1_out = (float*)d_out + BB*N_NODES*3;  // [B,N,8]

    char* w = (char*)d_ws;
    size_t off = 0;
    auto alloc = [&](size_t bytes) { void* p = w + off; off = align256(off + bytes); return p; };
    int*   cnt    = (int*)  alloc(N_NODES*4);
    float* stat1  = (float*)alloc(128*4);
    float* stat2  = (float*)alloc(16*4);
    size_t zero_bytes = off;
    float* dinv   = (float*)alloc(N_NODES*4);
    int*   incl   = (int*)  alloc(N_NODES*4);
    int*   part   = (int*)  alloc(64*4);
    int*   offs   = (int*)  alloc((N_NODES+1)*4);
    int*   cursor = (int*)  alloc(N_NODES*4);
    int*   csr_src= (int*)  alloc((size_t)N_EDGES*4);
    float* csr_w  = (float*)alloc((size_t)N_EDGES*4);
    float* xw     = (float*)alloc((size_t)ROWS*64*4);
    float* h      = (float*)alloc((size_t)ROWS*64*4);
    float* t2     = xw;      // alias: xw dead after k_prop1
    float* t3     = h;       // alias: h dead after k_bn1_gemm2
    (void)ws_size; (void)in_sizes; (void)n_in; (void)out_size;

    hipMemsetAsync(d_ws, 0, zero_bytes, stream);

    k_count <<<(N_EDGES+255)/256, 256, 0, stream>>>(ei, cnt);
    k_scanA <<<NSB, 1024, 0, stream>>>(cnt, incl, part, dinv);
    k_scanB <<<1, 64, 0, stream>>>(part);
    k_scanC <<<NSB, 1024, 0, stream>>>(cnt, incl, part, offs, cursor);
    k_fill  <<<(N_EDGES+255)/256, 256, 0, stream>>>(ei, dinv, cursor, csr_src, csr_w);

    k_gemm1 <<<ROWS/TM, 256, 0, stream>>>(x, W1, xw);
    k_prop1 <<<2048, 256, 0, stream>>>(xw, offs, csr_src, csr_w, dinv, b1, h, stat1);
    k_bn1_gemm2 <<<(ROWS+31)/32, 256, 0, stream>>>(h, stat1, g1, be1, W2, t2);
    k_prop2 <<<2048, 256, 0, stream>>>(t2, offs, csr_src, csr_w, dinv, b2, x1_out, stat2);
    k_bn2_gemm3 <<<(ROWS+255)/256, 256, 0, stream>>>(x1_out, stat2, g2, be2, W3, t3);
    k_prop3 <<<2048, 256, 0, stream>>>(t3, offs, csr_src, csr_w, dinv, b3, outp);
}

// Round 6
// 784.750 us; speedup vs baseline: 1.0074x; 1.0074x over previous
//
#include <hip/hip_runtime.h>
#include <stdint.h>

#define N_NODES 50000
#define N_EDGES 800000
#define BB 2
#define F0 216
#define ROWS (BB*N_NODES)   // 100000
#define BN_EPS 1e-5f
#define NSB 49              // ceil(N_NODES/1024)
#define KC2 12              // W chunk (double-buffered in registers)
#define TM 32               // gemm1 row tile: 100000 = 3125*32 exactly

// ---------------- CSR build ----------------
// edge_index arrives as int32 [2, E]

__global__ void k_count(const int* __restrict__ ei, int* __restrict__ cnt) {
    int e = blockIdx.x*blockDim.x + threadIdx.x;
    if (e < N_EDGES) {
        int c = ei[N_EDGES + e];
        atomicAdd(&cnt[c], 1);
    }
}

// scanA also produces dinv
__global__ void k_scanA(const int* __restrict__ cnt, int* __restrict__ incl, int* __restrict__ part,
                        float* __restrict__ dinv) {
    __shared__ int s[1024];
    int t = threadIdx.x;
    int i = blockIdx.x*1024 + t;
    int c = (i < N_NODES) ? cnt[i] : 0;
    if (i < N_NODES) dinv[i] = rsqrtf((float)(c + 1));  // +1 self loop
    s[t] = c;
    __syncthreads();
    for (int off=1; off<1024; off<<=1) {
        int a = (t >= off) ? s[t-off] : 0;
        __syncthreads();
        s[t] += a;
        __syncthreads();
    }
    if (i < N_NODES) incl[i] = s[t];
    if (t == 1023) part[blockIdx.x] = s[t];
}

__global__ void k_scanB(int* part) {
    if (threadIdx.x == 0 && blockIdx.x == 0) {
        int run = 0;
        for (int b=0; b<NSB; b++) { int v = part[b]; part[b] = run; run += v; }
    }
}

__global__ void k_scanC(const int* __restrict__ cnt, const int* __restrict__ incl, const int* __restrict__ part,
                        int* __restrict__ offs, int* __restrict__ cursor) {
    int i = blockIdx.x*1024 + threadIdx.x;
    if (i < N_NODES) {
        int inc = part[blockIdx.x] + incl[i];
        int ex = inc - cnt[i];
        offs[i] = ex; cursor[i] = ex;
        if (i == N_NODES-1) offs[N_NODES] = inc;
    }
}

__global__ void k_fill(const int* __restrict__ ei, const float* __restrict__ dinv,
                       int* __restrict__ cursor, int* __restrict__ csr_src, float* __restrict__ csr_w) {
    int e = blockIdx.x*blockDim.x + threadIdx.x;
    if (e < N_EDGES) {
        int r = ei[e];
        int c = ei[N_EDGES + e];
        int slot = atomicAdd(&cursor[c], 1);
        csr_src[slot] = r;
        csr_w[slot]  = dinv[r];
    }
}

// ---------------- Layer 1 GEMM: xw[100k,64] = x[100k,216] @ W1 ----------------
// v5: 32-row LDS tile (5 blocks/CU), coalesced staging, W double-buffered in
// registers. LAMBDA-FREE (round-5's by-reference lambda captures forced the W
// buffers into scratch: WRITE_SIZE 25MB->1GB). All array indices static.
__global__ __launch_bounds__(256,4) void k_gemm1(const float* __restrict__ x, const float* __restrict__ W1,
                                                 float* __restrict__ xw) {
    __shared__ float xs[TM*F0];        // 27648 B
    int t = threadIdx.x;
    int row0 = blockIdx.x * TM;        // exact tiling, no tail

    const float4* xg = reinterpret_cast<const float4*>(x + (size_t)row0 * F0);
    float4* xs4 = reinterpret_cast<float4*>(xs);
    #pragma unroll
    for (int i = 0; i < 7; i++) {
        int idx = t + i*256;
        if (idx < (TM*F0)/4) xs4[idx] = xg[idx];   // fully coalesced
    }
    __syncthreads();

    int o2 = t & 31;                   // cols o2, o2+32
    int rw = t >> 5;                   // 0..7 -> rows rw*4 .. rw*4+3
    float acc0[4] = {0.f,0.f,0.f,0.f};
    float acc1[4] = {0.f,0.f,0.f,0.f};
    float wA0[KC2], wB0[KC2], wA1[KC2], wB1[KC2];
    const float* xbase = xs + rw*4*F0;

    // prologue: chunk 0 -> buffer 0
    {
        const float* wp = W1 + o2;
        #pragma unroll
        for (int kk = 0; kk < KC2; kk++) {
            wA0[kk] = wp[kk*64];
            wB0[kk] = wp[kk*64 + 32];
        }
    }

    const int NCH = F0/KC2;            // 18 (even)
    for (int c = 0; c < NCH; c += 2) {
        // prefetch chunk c+1 -> buffer 1 (c+1 < NCH always: NCH even)
        {
            const float* wp = W1 + (size_t)(c+1)*KC2*64 + o2;
            #pragma unroll
            for (int kk = 0; kk < KC2; kk++) {
                wA1[kk] = wp[kk*64];
                wB1[kk] = wp[kk*64 + 32];
            }
        }
        // compute chunk c from buffer 0
        #pragma unroll
        for (int j = 0; j < 4; j++) {
            const float* xr = xbase + j*F0 + c*KC2;
            #pragma unroll
            for (int kq = 0; kq < KC2/4; kq++) {
                float4 xv = *reinterpret_cast<const float4*>(xr + 4*kq);
                acc0[j] += xv.x*wA0[4*kq] + xv.y*wA0[4*kq+1] + xv.z*wA0[4*kq+2] + xv.w*wA0[4*kq+3];
                acc1[j] += xv.x*wB0[4*kq] + xv.y*wB0[4*kq+1] + xv.z*wB0[4*kq+2] + xv.w*wB0[4*kq+3];
            }
        }
        // prefetch chunk c+2 -> buffer 0
        if (c+2 < NCH) {
            const float* wp = W1 + (size_t)(c+2)*KC2*64 + o2;
            #pragma unroll
            for (int kk = 0; kk < KC2; kk++) {
                wA0[kk] = wp[kk*64];
                wB0[kk] = wp[kk*64 + 32];
            }
        }
        // compute chunk c+1 from buffer 1
        #pragma unroll
        for (int j = 0; j < 4; j++) {
            const float* xr = xbase + j*F0 + (c+1)*KC2;
            #pragma unroll
            for (int kq = 0; kq < KC2/4; kq++) {
                float4 xv = *reinterpret_cast<const float4*>(xr + 4*kq);
                acc0[j] += xv.x*wA1[4*kq] + xv.y*wA1[4*kq+1] + xv.z*wA1[4*kq+2] + xv.w*wA1[4*kq+3];
                acc1[j] += xv.x*wB1[4*kq] + xv.y*wB1[4*kq+1] + xv.z*wB1[4*kq+2] + xv.w*wB1[4*kq+3];
            }
        }
    }

    #pragma unroll
    for (int j = 0; j < 4; j++) {
        int grow = row0 + rw*4 + j;
        xw[(size_t)grow*64 + o2]      = acc0[j];
        xw[(size_t)grow*64 + o2 + 32] = acc1[j];
    }
}

// ---------------- Propagate 1 (64 feat) + bias + relu + BN1 stats ----------------
// proven round-3 config: 4-deep unroll (8 gathers in flight), grid 2048
__global__ __launch_bounds__(256) void k_prop1(const float* __restrict__ xw, const int* __restrict__ offs,
                       const int* __restrict__ csr_src, const float* __restrict__ csr_w,
                       const float* __restrict__ dinv, const float* __restrict__ b1,
                       float* __restrict__ h, float* __restrict__ stat) {
    __shared__ float lsum[64], lsq[64];
    int t = threadIdx.x;
    if (t < 64) { lsum[t]=0.f; lsq[t]=0.f; }
    __syncthreads();
    int f = t & 63;
    int wid = blockIdx.x*4 + (t>>6);
    int nwaves = gridDim.x*4;
    float bias = b1[f];
    float ls=0.f, lq=0.f;
    for (int d = wid; d < N_NODES; d += nwaves) {
        int s0 = offs[d], s1 = offs[d+1];
        float a0=0.f, a1=0.f, p0=0.f, p1=0.f, q0=0.f, q1=0.f, r0=0.f, r1=0.f;
        int e = s0;
        for (; e+4 <= s1; e += 4) {
            int i0=csr_src[e], i1=csr_src[e+1], i2=csr_src[e+2], i3=csr_src[e+3];
            float w0=csr_w[e], w1=csr_w[e+1], w2=csr_w[e+2], w3=csr_w[e+3];
            a0 += w0*xw[(size_t)i0*64+f];  a1 += w0*xw[(size_t)(N_NODES+i0)*64+f];
            p0 += w1*xw[(size_t)i1*64+f];  p1 += w1*xw[(size_t)(N_NODES+i1)*64+f];
            q0 += w2*xw[(size_t)i2*64+f];  q1 += w2*xw[(size_t)(N_NODES+i2)*64+f];
            r0 += w3*xw[(size_t)i3*64+f];  r1 += w3*xw[(size_t)(N_NODES+i3)*64+f];
        }
        for (; e < s1; e++) {
            int src = csr_src[e]; float w = csr_w[e];
            a0 += w*xw[(size_t)src*64+f];  a1 += w*xw[(size_t)(N_NODES+src)*64+f];
        }
        a0 += p0 + q0 + r0;
        a1 += p1 + q1 + r1;
        float sd = dinv[d];
        a0 += sd * xw[(size_t)d*64 + f];
        a1 += sd * xw[(size_t)(N_NODES+d)*64 + f];
        float h0 = fmaxf(sd*a0 + bias, 0.f);
        float h1 = fmaxf(sd*a1 + bias, 0.f);
        h[(size_t)d*64 + f] = h0;
        h[(size_t)(N_NODES+d)*64 + f] = h1;
        ls += h0 + h1;
        lq += h0*h0 + h1*h1;
    }
    atomicAdd(&lsum[f], ls);
    atomicAdd(&lsq[f], lq);
    __syncthreads();
    if (t < 64) {
        atomicAdd(&stat[t],     lsum[t]);
        atomicAdd(&stat[64+t],  lsq[t]);
    }
}

// ---------------- BN1 finalize + apply + GEMM2 (64->8) ----------------
__global__ __launch_bounds__(256) void k_bn1_gemm2(const float* __restrict__ h, const float* __restrict__ stat,
                        const float* __restrict__ g, const float* __restrict__ be,
                        const float* __restrict__ W2, float* __restrict__ t2) {
    __shared__ float hs[32][68];
    __shared__ float w2s[64*8];
    __shared__ float scS[64], shS[64];
    int t = threadIdx.x;
    if (t < 64) {
        float inv_n = 1.0f / (float)(BB*N_NODES);
        float mean = stat[t]*inv_n;
        float var  = stat[64+t]*inv_n - mean*mean;
        float is   = rsqrtf(var + BN_EPS);
        float scale = g[t]*is;
        scS[t] = scale;
        shS[t] = be[t] - mean*scale;
    }
    for (int i=t; i<512; i+=256) w2s[i] = W2[i];
    __syncthreads();
    int row0 = blockIdx.x*32;
    for (int idx=t; idx<2048; idx+=256) {
        int r = idx>>6, f = idx&63;
        int grow = row0 + r;
        hs[r][f] = (grow < ROWS) ? h[(size_t)grow*64+f]*scS[f] + shS[f] : 0.f;
    }
    __syncthreads();
    int r = t >> 3, o = t & 7;
    float acc = 0.f;
    #pragma unroll
    for (int f=0; f<64; f++) acc += hs[r][f] * w2s[f*8+o];
    int grow = row0 + r;
    if (grow < ROWS) t2[(size_t)grow*8 + o] = acc;
}

// ---------------- Propagate 2 (8 feat) -> x1 out; relu + BN2 stats ----------------
__global__ __launch_bounds__(256) void k_prop2(const float* __restrict__ t2, const int* __restrict__ offs,
                       const int* __restrict__ csr_src, const float* __restrict__ csr_w,
                       const float* __restrict__ dinv, const float* __restrict__ b2,
                       float* __restrict__ x1_out, float* __restrict__ stat) {
    __shared__ float lsum[8], lsq[8];
    int t = threadIdx.x;
    if (t < 8) { lsum[t]=0.f; lsq[t]=0.f; }
    __syncthreads();
    int lane = t & 63;
    int o = lane & 7, b = (lane>>3)&1, es = lane>>4;   // 4 edge-lanes
    int wid = blockIdx.x*4 + (t>>6);
    int nwaves = gridDim.x*4;
    float bias = b2[o];
    float ls=0.f, lq=0.f;
    for (int d=wid; d<N_NODES; d+=nwaves) {
        int s0=offs[d], s1=offs[d+1];
        float accA=0.f, accB=0.f;
        int e = s0 + es;
        for (; e+4 < s1; e += 8) {
            accA += csr_w[e]   * t2[(size_t)(b*N_NODES+csr_src[e])*8 + o];
            accB += csr_w[e+4] * t2[(size_t)(b*N_NODES+csr_src[e+4])*8 + o];
        }
        if (e < s1) accA += csr_w[e] * t2[(size_t)(b*N_NODES+csr_src[e])*8 + o];
        float acc = accA + accB;
        acc += __shfl_xor(acc, 16, 64);
        acc += __shfl_xor(acc, 32, 64);
        float sd = dinv[d];
        float val = sd*(acc + sd*t2[(size_t)(b*N_NODES+d)*8 + o]) + bias;
        if (es == 0) {
            x1_out[(size_t)(b*N_NODES+d)*8 + o] = val;
            float rv = fmaxf(val, 0.f);
            ls += rv; lq += rv*rv;
        }
    }
    if (es == 0) { atomicAdd(&lsum[o], ls); atomicAdd(&lsq[o], lq); }
    __syncthreads();
    if (t < 8) { atomicAdd(&stat[t], lsum[t]); atomicAdd(&stat[8+t], lsq[t]); }
}

// ---------------- BN2 finalize + apply + GEMM3 (8->3), padded to 4 ----------------
__global__ void k_bn2_gemm3(const float* __restrict__ x1, const float* __restrict__ stat,
                            const float* __restrict__ g, const float* __restrict__ be,
                            const float* __restrict__ W3, float* __restrict__ t3) {
    int rowi = blockIdx.x*blockDim.x + threadIdx.x;
    if (rowi < ROWS) {
        float inv_n = 1.0f / (float)(BB*N_NODES);
        float v[8];
        #pragma unroll
        for (int o=0;o<8;o++) {
            float mean = stat[o]*inv_n;
            float var  = stat[8+o]*inv_n - mean*mean;
            float is   = rsqrtf(var + BN_EPS);
            float scale = g[o]*is;
            float shift = be[o] - mean*scale;
            float r = fmaxf(x1[(size_t)rowi*8+o], 0.f);
            v[o] = r*scale + shift;
        }
        #pragma unroll
        for (int c=0;c<3;c++) {
            float acc=0.f;
            #pragma unroll
            for (int o=0;o<8;o++) acc += v[o]*W3[o*3+c];
            t3[(size_t)rowi*4+c] = acc;
        }
        t3[(size_t)rowi*4+3] = 0.f;
    }
}

// ---------------- Propagate 3 (3 feat) + b3 -> final out ----------------
__global__ __launch_bounds__(256) void k_prop3(const float* __restrict__ t3, const int* __restrict__ offs,
                       const int* __restrict__ csr_src, const float* __restrict__ csr_w,
                       const float* __restrict__ dinv, const float* __restrict__ b3,
                       float* __restrict__ outp) {
    int t = threadIdx.x;
    int lane = t & 63;
    int c = lane & 3, b = (lane>>2)&1, es = lane>>3;   // 8 edge-lanes
    int wid = blockIdx.x*4 + (t>>6);
    int nwaves = gridDim.x*4;
    float bias = (c<3) ? b3[c] : 0.f;
    for (int d=wid; d<N_NODES; d+=nwaves) {
        int s0=offs[d], s1=offs[d+1];
        float accA=0.f, accB=0.f;
        int e = s0 + es;
        for (; e+8 < s1; e += 16) {
            accA += csr_w[e]   * t3[(size_t)(b*N_NODES+csr_src[e])*4 + c];
            accB += csr_w[e+8] * t3[(size_t)(b*N_NODES+csr_src[e+8])*4 + c];
        }
        if (e < s1) accA += csr_w[e] * t3[(size_t)(b*N_NODES+csr_src[e])*4 + c];
        float acc = accA + accB;
        acc += __shfl_xor(acc, 8, 64);
        acc += __shfl_xor(acc, 16, 64);
        acc += __shfl_xor(acc, 32, 64);
        float sd = dinv[d];
        float val = sd*(acc + sd*t3[(size_t)(b*N_NODES+d)*4 + c]) + bias;
        if (es == 0 && c < 3) outp[(size_t)(b*N_NODES+d)*3 + c] = val;
    }
}

// ---------------- launch ----------------
static inline size_t align256(size_t x){ return (x + 255) & ~(size_t)255; }

extern "C" void kernel_launch(void* const* d_in, const int* in_sizes, int n_in,
                              void* d_out, int out_size, void* d_ws, size_t ws_size,
                              hipStream_t stream) {
    const float* x   = (const float*)d_in[0];
    const float* W1  = (const float*)d_in[1];
    const float* b1  = (const float*)d_in[2];
    const float* g1  = (const float*)d_in[3];
    const float* be1 = (const float*)d_in[4];
    const float* W2  = (const float*)d_in[5];
    const float* b2  = (const float*)d_in[6];
    const float* g2  = (const float*)d_in[7];
    const float* be2 = (const float*)d_in[8];
    const float* W3  = (const float*)d_in[9];
    const float* b3  = (const float*)d_in[10];
    const int*   ei  = (const int*)d_in[11];     // int32 [2, E]

    float* outp   = (float*)d_out;                 // [B,N,3]
    float* x1_out = (float*)d_out + BB*N_NODES*3;  // [B,N,8]

    char* w = (char*)d_ws;
    size_t off = 0;
    auto alloc = [&](size_t bytes) { void* p = w + off; off = align256(off + bytes); return p; };
    int*   cnt    = (int*)  alloc(N_NODES*4);
    float* stat1  = (float*)alloc(128*4);
    float* stat2  = (float*)alloc(16*4);
    size_t zero_bytes = off;
    float* dinv   = (float*)alloc(N_NODES*4);
    int*   incl   = (int*)  alloc(N_NODES*4);
    int*   part   = (int*)  alloc(64*4);
    int*   offs   = (int*)  alloc((N_NODES+1)*4);
    int*   cursor = (int*)  alloc(N_NODES*4);
    int*   csr_src= (int*)  alloc((size_t)N_EDGES*4);
    float* csr_w  = (float*)alloc((size_t)N_EDGES*4);
    float* xw     = (float*)alloc((size_t)ROWS*64*4);
    float* h      = (float*)alloc((size_t)ROWS*64*4);
    float* t2     = xw;      // alias: xw dead after k_prop1
    float* t3     = h;       // alias: h dead after k_bn1_gemm2
    (void)ws_size; (void)in_sizes; (void)n_in; (void)out_size;

    hipMemsetAsync(d_ws, 0, zero_bytes, stream);

    k_count <<<(N_EDGES+255)/256, 256, 0, stream>>>(ei, cnt);
    k_scanA <<<NSB, 1024, 0, stream>>>(cnt, incl, part, dinv);
    k_scanB <<<1, 64, 0, stream>>>(part);
    k_scanC <<<NSB, 1024, 0, stream>>>(cnt, incl, part, offs, cursor);
    k_fill  <<<(N_EDGES+255)/256, 256, 0, stream>>>(ei, dinv, cursor, csr_src, csr_w);

    k_gemm1 <<<ROWS/TM, 256, 0, stream>>>(x, W1, xw);
    k_prop1 <<<2048, 256, 0, stream>>>(xw, offs, csr_src, csr_w, dinv, b1, h, stat1);
    k_bn1_gemm2 <<<(ROWS+31)/32, 256, 0, stream>>>(h, stat1, g1, be1, W2, t2);
    k_prop2 <<<2048, 256, 0, stream>>>(t2, offs, csr_src, csr_w, dinv, b2, x1_out, stat2);
    k_bn2_gemm3 <<<(ROWS+255)/256, 256, 0, stream>>>(x1_out, stat2, g2, be2, W3, t3);
    k_prop3 <<<2048, 256, 0, stream>>>(t3, offs, csr_src, csr_w, dinv, b3, outp);
}

// Round 8
// 525.406 us; speedup vs baseline: 1.5047x; 1.4936x over previous
//
#include <hip/hip_runtime.h>
#include <stdint.h>

#define N_NODES 50000
#define N_EDGES 800000
#define BB 2
#define F0 216
#define ROWS (BB*N_NODES)   // 100000
#define BN_EPS 1e-5f
#define NSB 49              // ceil(N_NODES/1024)
#define KC 12               // W chunk (single-buffered, fits 128-VGPR cap)
#define TM 32               // gemm1 row tile: 100000 = 3125*32 exactly

// ---------------- CSR build ----------------
// edge_index arrives as int32 [2, E]

__global__ void k_count(const int* __restrict__ ei, int* __restrict__ cnt) {
    int e = blockIdx.x*blockDim.x + threadIdx.x;
    if (e < N_EDGES) {
        int c = ei[N_EDGES + e];
        atomicAdd(&cnt[c], 1);
    }
}

// scanA also produces dinv
__global__ void k_scanA(const int* __restrict__ cnt, int* __restrict__ incl, int* __restrict__ part,
                        float* __restrict__ dinv) {
    __shared__ int s[1024];
    int t = threadIdx.x;
    int i = blockIdx.x*1024 + t;
    int c = (i < N_NODES) ? cnt[i] : 0;
    if (i < N_NODES) dinv[i] = rsqrtf((float)(c + 1));  // +1 self loop
    s[t] = c;
    __syncthreads();
    for (int off=1; off<1024; off<<=1) {
        int a = (t >= off) ? s[t-off] : 0;
        __syncthreads();
        s[t] += a;
        __syncthreads();
    }
    if (i < N_NODES) incl[i] = s[t];
    if (t == 1023) part[blockIdx.x] = s[t];
}

__global__ void k_scanB(int* part) {
    if (threadIdx.x == 0 && blockIdx.x == 0) {
        int run = 0;
        for (int b=0; b<NSB; b++) { int v = part[b]; part[b] = run; run += v; }
    }
}

__global__ void k_scanC(const int* __restrict__ cnt, const int* __restrict__ incl, const int* __restrict__ part,
                        int* __restrict__ offs, int* __restrict__ cursor) {
    int i = blockIdx.x*1024 + threadIdx.x;
    if (i < N_NODES) {
        int inc = part[blockIdx.x] + incl[i];
        int ex = inc - cnt[i];
        offs[i] = ex; cursor[i] = ex;
        if (i == N_NODES-1) offs[N_NODES] = inc;
    }
}

__global__ void k_fill(const int* __restrict__ ei, const float* __restrict__ dinv,
                       int* __restrict__ cursor, int* __restrict__ csr_src, float* __restrict__ csr_w) {
    int e = blockIdx.x*blockDim.x + threadIdx.x;
    if (e < N_EDGES) {
        int r = ei[e];
        int c = ei[N_EDGES + e];
        int slot = atomicAdd(&cursor[c], 1);
        csr_src[slot] = r;
        csr_w[slot]  = dinv[r];
    }
}

// ---------------- Layer 1 GEMM: xw[100k,64] = x[100k,216] @ W1 ----------------
// v6b: 32-row LDS tile, thread = 4 cols x 2 rows, W loaded as float4,
// single-buffer KC=12. Macro params renamed (no x/y/z/w collision).
#define FMA4(Acc, Sx, Wv) { Acc.x += (Sx)*(Wv).x; Acc.y += (Sx)*(Wv).y; Acc.z += (Sx)*(Wv).z; Acc.w += (Sx)*(Wv).w; }

__global__ __launch_bounds__(256,4) void k_gemm1(const float* __restrict__ x, const float* __restrict__ W1,
                                                 float* __restrict__ xw) {
    __shared__ float xs[TM*F0];        // 27648 B -> 5 blocks/CU by LDS
    int t = threadIdx.x;
    int row0 = blockIdx.x * TM;        // exact tiling, no tail

    const float4* xg = reinterpret_cast<const float4*>(x + (size_t)row0 * F0);
    float4* xs4 = reinterpret_cast<float4*>(xs);
    #pragma unroll
    for (int i = 0; i < 7; i++) {
        int idx = t + i*256;
        if (idx < (TM*F0)/4) xs4[idx] = xg[idx];   // fully coalesced
    }
    __syncthreads();

    int og = t & 15;                   // col group: cols 4*og .. 4*og+3
    int rg = t >> 4;                   // 0..15 -> rows rg*2, rg*2+1
    const float4* W4 = reinterpret_cast<const float4*>(W1);   // [216][16] of float4
    float4 a0 = {0.f,0.f,0.f,0.f};
    float4 a1 = {0.f,0.f,0.f,0.f};
    const float* xr0 = xs + (rg*2+0)*F0;
    const float* xr1 = xs + (rg*2+1)*F0;

    for (int kc = 0; kc < F0; kc += KC) {
        float4 wv[KC];
        #pragma unroll
        for (int kk = 0; kk < KC; kk++)
            wv[kk] = W4[(size_t)(kc+kk)*16 + og];
        #pragma unroll
        for (int kq = 0; kq < KC/4; kq++) {
            float4 xv0 = *reinterpret_cast<const float4*>(xr0 + kc + 4*kq);
            float4 xv1 = *reinterpret_cast<const float4*>(xr1 + kc + 4*kq);
            FMA4(a0, xv0.x, wv[4*kq+0]); FMA4(a0, xv0.y, wv[4*kq+1]);
            FMA4(a0, xv0.z, wv[4*kq+2]); FMA4(a0, xv0.w, wv[4*kq+3]);
            FMA4(a1, xv1.x, wv[4*kq+0]); FMA4(a1, xv1.y, wv[4*kq+1]);
            FMA4(a1, xv1.z, wv[4*kq+2]); FMA4(a1, xv1.w, wv[4*kq+3]);
        }
    }

    float4* out4 = reinterpret_cast<float4*>(xw);
    out4[(size_t)(row0 + rg*2    )*16 + og] = a0;
    out4[(size_t)(row0 + rg*2 + 1)*16 + og] = a1;
}

// ---------------- Propagate 1 (64 feat) + bias + relu + BN1 stats ----------------
// proven round-3 config: 4-deep unroll (8 gathers in flight), grid 2048
__global__ __launch_bounds__(256) void k_prop1(const float* __restrict__ xw, const int* __restrict__ offs,
                       const int* __restrict__ csr_src, const float* __restrict__ csr_w,
                       const float* __restrict__ dinv, const float* __restrict__ b1,
                       float* __restrict__ h, float* __restrict__ stat) {
    __shared__ float lsum[64], lsq[64];
    int t = threadIdx.x;
    if (t < 64) { lsum[t]=0.f; lsq[t]=0.f; }
    __syncthreads();
    int f = t & 63;
    int wid = blockIdx.x*4 + (t>>6);
    int nwaves = gridDim.x*4;
    float bias = b1[f];
    float ls=0.f, lq=0.f;
    for (int d = wid; d < N_NODES; d += nwaves) {
        int s0 = offs[d], s1 = offs[d+1];
        float a0=0.f, a1=0.f, p0=0.f, p1=0.f, q0=0.f, q1=0.f, r0=0.f, r1=0.f;
        int e = s0;
        for (; e+4 <= s1; e += 4) {
            int i0=csr_src[e], i1=csr_src[e+1], i2=csr_src[e+2], i3=csr_src[e+3];
            float w0=csr_w[e], w1=csr_w[e+1], w2=csr_w[e+2], w3=csr_w[e+3];
            a0 += w0*xw[(size_t)i0*64+f];  a1 += w0*xw[(size_t)(N_NODES+i0)*64+f];
            p0 += w1*xw[(size_t)i1*64+f];  p1 += w1*xw[(size_t)(N_NODES+i1)*64+f];
            q0 += w2*xw[(size_t)i2*64+f];  q1 += w2*xw[(size_t)(N_NODES+i2)*64+f];
            r0 += w3*xw[(size_t)i3*64+f];  r1 += w3*xw[(size_t)(N_NODES+i3)*64+f];
        }
        for (; e < s1; e++) {
            int src = csr_src[e]; float w = csr_w[e];
            a0 += w*xw[(size_t)src*64+f];  a1 += w*xw[(size_t)(N_NODES+src)*64+f];
        }
        a0 += p0 + q0 + r0;
        a1 += p1 + q1 + r1;
        float sd = dinv[d];
        a0 += sd * xw[(size_t)d*64 + f];
        a1 += sd * xw[(size_t)(N_NODES+d)*64 + f];
        float h0 = fmaxf(sd*a0 + bias, 0.f);
        float h1 = fmaxf(sd*a1 + bias, 0.f);
        h[(size_t)d*64 + f] = h0;
        h[(size_t)(N_NODES+d)*64 + f] = h1;
        ls += h0 + h1;
        lq += h0*h0 + h1*h1;
    }
    atomicAdd(&lsum[f], ls);
    atomicAdd(&lsq[f], lq);
    __syncthreads();
    if (t < 64) {
        atomicAdd(&stat[t],     lsum[t]);
        atomicAdd(&stat[64+t],  lsq[t]);
    }
}

// ---------------- BN1 finalize + apply + GEMM2 (64->8) ----------------
__global__ __launch_bounds__(256) void k_bn1_gemm2(const float* __restrict__ h, const float* __restrict__ stat,
                        const float* __restrict__ g, const float* __restrict__ be,
                        const float* __restrict__ W2, float* __restrict__ t2) {
    __shared__ float hs[32][68];
    __shared__ float w2s[64*8];
    __shared__ float scS[64], shS[64];
    int t = threadIdx.x;
    if (t < 64) {
        float inv_n = 1.0f / (float)(BB*N_NODES);
        float mean = stat[t]*inv_n;
        float var  = stat[64+t]*inv_n - mean*mean;
        float is   = rsqrtf(var + BN_EPS);
        float scale = g[t]*is;
        scS[t] = scale;
        shS[t] = be[t] - mean*scale;
    }
    for (int i=t; i<512; i+=256) w2s[i] = W2[i];
    __syncthreads();
    int row0 = blockIdx.x*32;
    for (int idx=t; idx<2048; idx+=256) {
        int r = idx>>6, f = idx&63;
        int grow = row0 + r;
        hs[r][f] = (grow < ROWS) ? h[(size_t)grow*64+f]*scS[f] + shS[f] : 0.f;
    }
    __syncthreads();
    int r = t >> 3, o = t & 7;
    float acc = 0.f;
    #pragma unroll
    for (int f=0; f<64; f++) acc += hs[r][f] * w2s[f*8+o];
    int grow = row0 + r;
    if (grow < ROWS) t2[(size_t)grow*8 + o] = acc;
}

// ---------------- Propagate 2 (8 feat) -> x1 out; relu + BN2 stats ----------------
__global__ __launch_bounds__(256) void k_prop2(const float* __restrict__ t2, const int* __restrict__ offs,
                       const int* __restrict__ csr_src, const float* __restrict__ csr_w,
                       const float* __restrict__ dinv, const float* __restrict__ b2,
                       float* __restrict__ x1_out, float* __restrict__ stat) {
    __shared__ float lsum[8], lsq[8];
    int t = threadIdx.x;
    if (t < 8) { lsum[t]=0.f; lsq[t]=0.f; }
    __syncthreads();
    int lane = t & 63;
    int o = lane & 7, b = (lane>>3)&1, es = lane>>4;   // 4 edge-lanes
    int wid = blockIdx.x*4 + (t>>6);
    int nwaves = gridDim.x*4;
    float bias = b2[o];
    float ls=0.f, lq=0.f;
    for (int d=wid; d<N_NODES; d+=nwaves) {
        int s0=offs[d], s1=offs[d+1];
        float accA=0.f, accB=0.f;
        int e = s0 + es;
        for (; e+4 < s1; e += 8) {
            accA += csr_w[e]   * t2[(size_t)(b*N_NODES+csr_src[e])*8 + o];
            accB += csr_w[e+4] * t2[(size_t)(b*N_NODES+csr_src[e+4])*8 + o];
        }
        if (e < s1) accA += csr_w[e] * t2[(size_t)(b*N_NODES+csr_src[e])*8 + o];
        float acc = accA + accB;
        acc += __shfl_xor(acc, 16, 64);
        acc += __shfl_xor(acc, 32, 64);
        float sd = dinv[d];
        float val = sd*(acc + sd*t2[(size_t)(b*N_NODES+d)*8 + o]) + bias;
        if (es == 0) {
            x1_out[(size_t)(b*N_NODES+d)*8 + o] = val;
            float rv = fmaxf(val, 0.f);
            ls += rv; lq += rv*rv;
        }
    }
    if (es == 0) { atomicAdd(&lsum[o], ls); atomicAdd(&lsq[o], lq); }
    __syncthreads();
    if (t < 8) { atomicAdd(&stat[t], lsum[t]); atomicAdd(&stat[8+t], lsq[t]); }
}

// ---------------- BN2 finalize + apply + GEMM3 (8->3), padded to 4 ----------------
__global__ void k_bn2_gemm3(const float* __restrict__ x1, const float* __restrict__ stat,
                            const float* __restrict__ g, const float* __restrict__ be,
                            const float* __restrict__ W3, float* __restrict__ t3) {
    int rowi = blockIdx.x*blockDim.x + threadIdx.x;
    if (rowi < ROWS) {
        float inv_n = 1.0f / (float)(BB*N_NODES);
        float v[8];
        #pragma unroll
        for (int o=0;o<8;o++) {
            float mean = stat[o]*inv_n;
            float var  = stat[8+o]*inv_n - mean*mean;
            float is   = rsqrtf(var + BN_EPS);
            float scale = g[o]*is;
            float shift = be[o] - mean*scale;
            float r = fmaxf(x1[(size_t)rowi*8+o], 0.f);
            v[o] = r*scale + shift;
        }
        #pragma unroll
        for (int c=0;c<3;c++) {
            float acc=0.f;
            #pragma unroll
            for (int o=0;o<8;o++) acc += v[o]*W3[o*3+c];
            t3[(size_t)rowi*4+c] = acc;
        }
        t3[(size_t)rowi*4+3] = 0.f;
    }
}

// ---------------- Propagate 3 (3 feat) + b3 -> final out ----------------
__global__ __launch_bounds__(256) void k_prop3(const float* __restrict__ t3, const int* __restrict__ offs,
                       const int* __restrict__ csr_src, const float* __restrict__ csr_w,
                       const float* __restrict__ dinv, const float* __restrict__ b3,
                       float* __restrict__ outp) {
    int t = threadIdx.x;
    int lane = t & 63;
    int c = lane & 3, b = (lane>>2)&1, es = lane>>3;   // 8 edge-lanes
    int wid = blockIdx.x*4 + (t>>6);
    int nwaves = gridDim.x*4;
    float bias = (c<3) ? b3[c] : 0.f;
    for (int d=wid; d<N_NODES; d+=nwaves) {
        int s0=offs[d], s1=offs[d+1];
        float accA=0.f, accB=0.f;
        int e = s0 + es;
        for (; e+8 < s1; e += 16) {
            accA += csr_w[e]   * t3[(size_t)(b*N_NODES+csr_src[e])*4 + c];
            accB += csr_w[e+8] * t3[(size_t)(b*N_NODES+csr_src[e+8])*4 + c];
        }
        if (e < s1) accA += csr_w[e] * t3[(size_t)(b*N_NODES+csr_src[e])*4 + c];
        float acc = accA + accB;
        acc += __shfl_xor(acc, 8, 64);
        acc += __shfl_xor(acc, 16, 64);
        acc += __shfl_xor(acc, 32, 64);
        float sd = dinv[d];
        float val = sd*(acc + sd*t3[(size_t)(b*N_NODES+d)*4 + c]) + bias;
        if (es == 0 && c < 3) outp[(size_t)(b*N_NODES+d)*3 + c] = val;
    }
}

// ---------------- launch ----------------
static inline size_t align256(size_t x){ return (x + 255) & ~(size_t)255; }

extern "C" void kernel_launch(void* const* d_in, const int* in_sizes, int n_in,
                              void* d_out, int out_size, void* d_ws, size_t ws_size,
                              hipStream_t stream) {
    const float* x   = (const float*)d_in[0];
    const float* W1  = (const float*)d_in[1];
    const float* b1  = (const float*)d_in[2];
    const float* g1  = (const float*)d_in[3];
    const float* be1 = (const float*)d_in[4];
    const float* W2  = (const float*)d_in[5];
    const float* b2  = (const float*)d_in[6];
    const float* g2  = (const float*)d_in[7];
    const float* be2 = (const float*)d_in[8];
    const float* W3  = (const float*)d_in[9];
    const float* b3  = (const float*)d_in[10];
    const int*   ei  = (const int*)d_in[11];     // int32 [2, E]

    float* outp   = (float*)d_out;                 // [B,N,3]
    float* x1_out = (float*)d_out + BB*N_NODES*3;  // [B,N,8]

    char* w = (char*)d_ws;
    size_t off = 0;
    auto alloc = [&](size_t bytes) { void* p = w + off; off = align256(off + bytes); return p; };
    int*   cnt    = (int*)  alloc(N_NODES*4);
    float* stat1  = (float*)alloc(128*4);
    float* stat2  = (float*)alloc(16*4);
    size_t zero_bytes = off;
    float* dinv   = (float*)alloc(N_NODES*4);
    int*   incl   = (int*)  alloc(N_NODES*4);
    int*   part   = (int*)  alloc(64*4);
    int*   offs   = (int*)  alloc((N_NODES+1)*4);
    int*   cursor = (int*)  alloc(N_NODES*4);
    int*   csr_src= (int*)  alloc((size_t)N_EDGES*4);
    float* csr_w  = (float*)alloc((size_t)N_EDGES*4);
    float* xw     = (float*)alloc((size_t)ROWS*64*4);
    float* h      = (float*)alloc((size_t)ROWS*64*4);
    float* t2     = xw;      // alias: xw dead after k_prop1
    float* t3     = h;       // alias: h dead after k_bn1_gemm2
    (void)ws_size; (void)in_sizes; (void)n_in; (void)out_size;

    hipMemsetAsync(d_ws, 0, zero_bytes, stream);

    k_count <<<(N_EDGES+255)/256, 256, 0, stream>>>(ei, cnt);
    k_scanA <<<NSB, 1024, 0, stream>>>(cnt, incl, part, dinv);
    k_scanB <<<1, 64, 0, stream>>>(part);
    k_scanC <<<NSB, 1024, 0, stream>>>(cnt, incl, part, offs, cursor);
    k_fill  <<<(N_EDGES+255)/256, 256, 0, stream>>>(ei, dinv, cursor, csr_src, csr_w);

    k_gemm1 <<<ROWS/TM, 256, 0, stream>>>(x, W1, xw);
    k_prop1 <<<2048, 256, 0, stream>>>(xw, offs, csr_src, csr_w, dinv, b1, h, stat1);
    k_bn1_gemm2 <<<(ROWS+31)/32, 256, 0, stream>>>(h, stat1, g1, be1, W2, t2);
    k_prop2 <<<2048, 256, 0, stream>>>(t2, offs, csr_src, csr_w, dinv, b2, x1_out, stat2);
    k_bn2_gemm3 <<<(ROWS+255)/256, 256, 0, stream>>>(x1_out, stat2, g2, be2, W3, t3);
    k_prop3 <<<2048, 256, 0, stream>>>(t3, offs, csr_src, csr_w, dinv, b3, outp);
}